// Round 10
// baseline (322.751 us; speedup 1.0000x reference)
//
#include <hip/hip_runtime.h>
#include <hip/hip_fp16.h>

#define N_SEQ 8192
#define E_DIM 768
#define D_OUT 64
#define PADK 68                       // 64 + 4 pad -> 136B rows: 2-way (free) bank aliasing
#define SCALE_LOG2 0.18033688011112042f   // 1/(8*ln2): fold softmax scale + log2e into Q

typedef __attribute__((ext_vector_type(8)))  short s16x8;
typedef __attribute__((ext_vector_type(4)))  float f32x4;
typedef __attribute__((ext_vector_type(16))) float f32x16;

static __device__ __forceinline__ unsigned short f2bf(float f) {
    union { float f; unsigned int u; } v; v.f = f;
    unsigned int r = v.u + 0x7FFFu + ((v.u >> 16) & 1u);   // RNE
    return (unsigned short)(r >> 16);
}
static __device__ __forceinline__ float bf2f(unsigned short h) {
    union { float f; unsigned int u; } v; v.u = ((unsigned int)h) << 16; return v.f;
}
// pack two f32 -> bf16x2 by truncation (bias cancels: same P feeds O and l)
static __device__ __forceinline__ unsigned int packbf(float a, float b) {
    union { float f; unsigned int u; } x, y; x.f = a; y.f = b;
    return (y.u & 0xFFFF0000u) | (x.u >> 16);
}
static __device__ __forceinline__ s16x8 gfrag(const unsigned short* p) {
    union { uint4 u; s16x8 s; } r; r.u = *(const uint4*)p; return r.s;
}
static __device__ __forceinline__ s16x8 ldsfrag(const unsigned short* p) {
    union { uint2 u[2]; s16x8 s; } r;
    r.u[0] = *(const uint2*)(p);
    r.u[1] = *(const uint2*)(p + 4);
    return r.s;
}
static __device__ __forceinline__ void st32(unsigned short* d, uint4 a, uint4 b) {
    uint2* p = (uint2*)d;
    p[0] = make_uint2(a.x, a.y); p[1] = make_uint2(a.z, a.w);
    p[2] = make_uint2(b.x, b.y); p[3] = make_uint2(b.z, b.w);
}

// ---------------- Kernel 1: W -> Wt (transposed, bf16 hi/lo) -----------------
__global__ __launch_bounds__(256) void prep_w(const float* __restrict__ WQ,
                                              const float* __restrict__ WK,
                                              const float* __restrict__ WV,
                                              unsigned short* __restrict__ Wthi,
                                              unsigned short* __restrict__ Wtlo) {
    int idx = blockIdx.x * 256 + threadIdx.x;          // 192*768 total
    if (idx >= 192 * E_DIM) return;
    int n = idx / E_DIM;
    int k = idx - n * E_DIM;
    float v;
    if (n < 64)       v = WQ[k * 64 + n];
    else if (n < 128) v = WK[k * 64 + (n - 64)];
    else              v = WV[k * 64 + (n - 128)];
    unsigned short hb = f2bf(v);
    Wthi[idx] = hb;
    Wtlo[idx] = f2bf(v - bf2f(hb));
}

// ---------------- Kernel 2: QKV projection (X f32 in, convert in-reg) --------
__global__ __launch_bounds__(256, 2) void proj_qkv(const float* __restrict__ X,
                                                   const unsigned short* __restrict__ Wthi,
                                                   const unsigned short* __restrict__ Wtlo,
                                                   unsigned short* __restrict__ Qhi,
                                                   unsigned short* __restrict__ Qlo,
                                                   unsigned short* __restrict__ Khi,
                                                   unsigned short* __restrict__ Klo,
                                                   unsigned short* __restrict__ Vt) {
    int tid  = threadIdx.x;
    int wv   = tid >> 6;
    int lane = tid & 63;
    int id   = blockIdx.x * 4 + wv;          // 0..2047
    int mt   = id >> 2;
    int c    = id & 3;                       // 16-col block within D=64
    int m0 = mt * 16, n0 = c * 16;
    int lr = lane & 15, lk = lane >> 4;      // row-in-tile, k-quad

    f32x4 aQ, aK, aV;
    #pragma unroll
    for (int i = 0; i < 4; ++i) { aQ[i] = 0.f; aK[i] = 0.f; aV[i] = 0.f; }

    const float*          xp  = X    + (size_t)(m0 + lr) * E_DIM + lk * 8;
    const unsigned short* wqh = Wthi + (size_t)(n0 + lr) * E_DIM + lk * 8;
    const unsigned short* wql = Wtlo + (size_t)(n0 + lr) * E_DIM + lk * 8;
    const unsigned short* wkh = Wthi + (size_t)(64 + n0 + lr) * E_DIM + lk * 8;
    const unsigned short* wkl = Wtlo + (size_t)(64 + n0 + lr) * E_DIM + lk * 8;
    const unsigned short* wvh = Wthi + (size_t)(128 + n0 + lr) * E_DIM + lk * 8;

    #pragma unroll 2
    for (int ks = 0; ks < E_DIM / 32; ++ks) {
        int kb = ks * 32;
        float4 x0 = *(const float4*)(xp + kb);
        float4 x1 = *(const float4*)(xp + kb + 4);
        s16x8 bqh = gfrag(wqh + kb);
        s16x8 bql = gfrag(wql + kb);
        s16x8 bkh = gfrag(wkh + kb);
        s16x8 bkl = gfrag(wkl + kb);
        s16x8 bvh = gfrag(wvh + kb);
        // split X f32 -> hi/lo bf16 fragments (bit-identical to old prep_x)
        float xs[8] = { x0.x, x0.y, x0.z, x0.w, x1.x, x1.y, x1.z, x1.w };
        union { unsigned short u[8]; s16x8 s; } ah, al;
        #pragma unroll
        for (int i = 0; i < 8; ++i) {
            unsigned short hb = f2bf(xs[i]);
            ah.u[i] = hb;
            al.u[i] = f2bf(xs[i] - bf2f(hb));
        }
        aQ = __builtin_amdgcn_mfma_f32_16x16x32_bf16(ah.s, bqh, aQ, 0, 0, 0);
        aK = __builtin_amdgcn_mfma_f32_16x16x32_bf16(ah.s, bkh, aK, 0, 0, 0);
        aV = __builtin_amdgcn_mfma_f32_16x16x32_bf16(ah.s, bvh, aV, 0, 0, 0);
        aQ = __builtin_amdgcn_mfma_f32_16x16x32_bf16(ah.s, bql, aQ, 0, 0, 0);
        aK = __builtin_amdgcn_mfma_f32_16x16x32_bf16(ah.s, bkl, aK, 0, 0, 0);
        aQ = __builtin_amdgcn_mfma_f32_16x16x32_bf16(al.s, bqh, aQ, 0, 0, 0);
        aK = __builtin_amdgcn_mfma_f32_16x16x32_bf16(al.s, bkh, aK, 0, 0, 0);
    }

    // C/D layout (16x16): col = lane&15, row = (lane>>4)*4 + r  [m89/m91]
    #pragma unroll
    for (int r = 0; r < 4; ++r) {
        int grow = m0 + lk * 4 + r, gcol = n0 + lr;
        float q = aQ[r] * SCALE_LOG2;
        unsigned short hb = f2bf(q);
        Qhi[(size_t)grow * 64 + gcol] = hb;
        Qlo[(size_t)grow * 64 + gcol] = f2bf(q - bf2f(hb));
        float v = aK[r];
        hb = f2bf(v);
        Khi[(size_t)grow * 64 + gcol] = hb;
        Klo[(size_t)grow * 64 + gcol] = f2bf(v - bf2f(hb));
    }
    ushort4 pk;                          // V: 4 consecutive rows -> one 8B store
    pk.x = f2bf(aV[0]); pk.y = f2bf(aV[1]);
    pk.z = f2bf(aV[2]); pk.w = f2bf(aV[3]);
    *(ushort4*)(Vt + (size_t)(n0 + lr) * N_SEQ + m0 + lk * 4) = pk;
}

// ---------------- Kernel 3: flash attention (round-0 body, bf16 Opart) -------
// grid (nsplit, 64); block 256 = 4 waves x 32 Q-rows; PADK layout (0 conflicts).
// __launch_bounds__(256,3): REQUIRED -- (256,4) makes hipcc clamp to 64 VGPR
// and spill to scratch (rounds 4 & 7). P half-swap: verified shfl_xor path
// (v_permlane32_swap retired -- both operand orientations failed on HW, r1/r9).
__global__ __launch_bounds__(256, 3) void attn(const unsigned short* __restrict__ Qhi,
                                               const unsigned short* __restrict__ Qlo,
                                               const unsigned short* __restrict__ Khi,
                                               const unsigned short* __restrict__ Klo,
                                               const unsigned short* __restrict__ Vt,
                                               unsigned short* __restrict__ Opart,
                                               float* __restrict__ mpart,
                                               float* __restrict__ lpart,
                                               int chunk) {
    __shared__ unsigned short sK[128 * PADK];   // rows 0-63 Khi, 64-127 Klo
    __shared__ unsigned short sV [64 * PADK];   // [d][key]

    int tid = threadIdx.x, wv = tid >> 6, lane = tid & 63;
    int lrow = lane & 31, lh = lane >> 5;
    int c = blockIdx.x, qb = blockIdx.y;
    int q0 = qb * 128 + wv * 32;

    // Q fragments (whole D=64) resident in registers
    s16x8 qh[4], ql[4];
    #pragma unroll
    for (int ks = 0; ks < 4; ++ks) {
        int kb = ks * 16 + lh * 8;
        qh[ks] = gfrag(Qhi + (size_t)(q0 + lrow) * 64 + kb);
        ql[ks] = gfrag(Qlo + (size_t)(q0 + lrow) * 64 + kb);
    }

    f32x16 O0, O1;
    #pragma unroll
    for (int i = 0; i < 16; ++i) { O0[i] = 0.f; O1[i] = 0.f; }
    float mrow = -1e30f, lrun = 0.f;

    int steps = chunk >> 6;
    int srow = tid >> 2, sseg = tid & 3;    // staging: 64 rows x 4 segs x 16 elems

    // prefetch tile 0
    uint4 rA0, rA1, rB0, rB1, rC0, rC1;
    {
        int j1 = c * chunk;
        const uint4* ps = (const uint4*)(Khi + ((size_t)(j1 + srow) * 64 + sseg * 16));
        rA0 = ps[0]; rA1 = ps[1];
        ps = (const uint4*)(Klo + ((size_t)(j1 + srow) * 64 + sseg * 16));
        rB0 = ps[0]; rB1 = ps[1];
        ps = (const uint4*)(Vt + ((size_t)srow * N_SEQ + j1 + sseg * 16));
        rC0 = ps[0]; rC1 = ps[1];
    }

    for (int it = 0; it < steps; ++it) {
        __syncthreads();                     // all waves done reading prev tile
        st32(sK + srow * PADK + sseg * 16, rA0, rA1);
        st32(sK + (64 + srow) * PADK + sseg * 16, rB0, rB1);
        st32(sV + srow * PADK + sseg * 16, rC0, rC1);
        __syncthreads();

        if (it + 1 < steps) {                // prefetch next tile (waits at next st32)
            int j1 = c * chunk + (it + 1) * 64;
            const uint4* ps = (const uint4*)(Khi + ((size_t)(j1 + srow) * 64 + sseg * 16));
            rA0 = ps[0]; rA1 = ps[1];
            ps = (const uint4*)(Klo + ((size_t)(j1 + srow) * 64 + sseg * 16));
            rB0 = ps[0]; rB1 = ps[1];
            ps = (const uint4*)(Vt + ((size_t)srow * N_SEQ + j1 + sseg * 16));
            rC0 = ps[0]; rC1 = ps[1];
        }

        // S^T = K @ Q^T  (3-term split-bf16): s0 keys 0-31, s1 keys 32-63
        f32x16 s0, s1;
        #pragma unroll
        for (int i = 0; i < 16; ++i) { s0[i] = 0.f; s1[i] = 0.f; }
        #pragma unroll
        for (int ks = 0; ks < 4; ++ks) {
            int kb = ks * 16 + lh * 8;
            s16x8 b0h = ldsfrag(sK + (size_t)lrow * PADK + kb);
            s16x8 b0l = ldsfrag(sK + (size_t)(64 + lrow) * PADK + kb);
            s0 = __builtin_amdgcn_mfma_f32_32x32x16_bf16(b0h, qh[ks], s0, 0, 0, 0);
            s0 = __builtin_amdgcn_mfma_f32_32x32x16_bf16(b0l, qh[ks], s0, 0, 0, 0);
            s0 = __builtin_amdgcn_mfma_f32_32x32x16_bf16(b0h, ql[ks], s0, 0, 0, 0);
            s16x8 b1h = ldsfrag(sK + (size_t)(32 + lrow) * PADK + kb);
            s16x8 b1l = ldsfrag(sK + (size_t)(96 + lrow) * PADK + kb);
            s1 = __builtin_amdgcn_mfma_f32_32x32x16_bf16(b1h, qh[ks], s1, 0, 0, 0);
            s1 = __builtin_amdgcn_mfma_f32_32x32x16_bf16(b1l, qh[ks], s1, 0, 0, 0);
            s1 = __builtin_amdgcn_mfma_f32_32x32x16_bf16(b1h, ql[ks], s1, 0, 0, 0);
        }

        // in-lane row max (this lane's query = lrow; 32 of 64 keys per half)
        float rm = s0[0];
        #pragma unroll
        for (int i = 1; i < 16; ++i) rm = fmaxf(rm, s0[i]);
        #pragma unroll
        for (int i = 0; i < 16; ++i) rm = fmaxf(rm, s1[i]);
        rm = fmaxf(rm, __shfl_xor(rm, 32, 64));
        float mn  = fmaxf(mrow, rm);
        float alf = exp2f(mrow - mn);
        mrow = mn;

        // p = exp2(s - m) in place; partial row-sum
        float psum = 0.f;
        #pragma unroll
        for (int i = 0; i < 16; ++i) { s0[i] = exp2f(s0[i] - mn); psum += s0[i]; }
        #pragma unroll
        for (int i = 0; i < 16; ++i) { s1[i] = exp2f(s1[i] - mn); psum += s1[i]; }
        lrun = lrun * alf + psum;

        // pack P to bf16 pairs; swap halves via lane^32 to build A-frags
        unsigned int I[16], J[16];
        #pragma unroll
        for (int q4 = 0; q4 < 4; ++q4) {
            I[2 * q4]     = packbf(s0[4 * q4],     s0[4 * q4 + 1]);
            I[2 * q4 + 1] = packbf(s0[4 * q4 + 2], s0[4 * q4 + 3]);
            I[8 + 2 * q4]     = packbf(s1[4 * q4],     s1[4 * q4 + 1]);
            I[8 + 2 * q4 + 1] = packbf(s1[4 * q4 + 2], s1[4 * q4 + 3]);
        }
        #pragma unroll
        for (int i = 0; i < 16; ++i) J[i] = (unsigned int)__shfl_xor((int)I[i], 32, 64);
        s16x8 a[4];
        #pragma unroll
        for (int ks = 0; ks < 4; ++ks) {
            int b = (ks >> 1) * 8 + (ks & 1) * 4;
            union { unsigned int u[4]; s16x8 s; } fa;
            fa.u[0] = lh ? J[b + 2] : I[b];
            fa.u[1] = lh ? J[b + 3] : I[b + 1];
            fa.u[2] = lh ? I[b + 2] : J[b];
            fa.u[3] = lh ? I[b + 3] : J[b + 1];
            a[ks] = fa.s;
        }

        // rescale O by alpha of each O-row's query (fetch via bpermute)
        #pragma unroll
        for (int r = 0; r < 16; ++r) {
            int qr = (r & 3) + 8 * (r >> 2) + 4 * lh;
            float af = __shfl(alf, qr, 64);
            O0[r] *= af; O1[r] *= af;
        }

        // O += P @ V
        #pragma unroll
        for (int ks = 0; ks < 4; ++ks) {
            int kb = ks * 16 + lh * 8;
            s16x8 b0 = ldsfrag(sV + (size_t)lrow * PADK + kb);
            s16x8 b1 = ldsfrag(sV + (size_t)(32 + lrow) * PADK + kb);
            O0 = __builtin_amdgcn_mfma_f32_32x32x16_bf16(a[ks], b0, O0, 0, 0, 0);
            O1 = __builtin_amdgcn_mfma_f32_32x32x16_bf16(a[ks], b1, O1, 0, 0, 0);
        }
    }

    // store partials (bf16)
    #pragma unroll
    for (int r = 0; r < 16; ++r) {
        int row = (r & 3) + 8 * (r >> 2) + 4 * lh;
        int grow = q0 + row;
        size_t ob = ((size_t)c * N_SEQ + grow) * 64;
        Opart[ob + lrow]      = f2bf(O0[r]);
        Opart[ob + 32 + lrow] = f2bf(O1[r]);
    }
    float lfull = lrun + __shfl_xor(lrun, 32, 64);
    if (lane < 32) {
        int grow = q0 + lrow;
        mpart[c * N_SEQ + grow] = mrow;
        lpart[c * N_SEQ + grow] = lfull;
    }
}

// ---------------- Kernel 4: combine split-K partials (bf16 in, f32 out) ------
__global__ __launch_bounds__(256) void combine(const unsigned short* __restrict__ Opart,
                                               const float* __restrict__ mpart,
                                               const float* __restrict__ lpart,
                                               float* __restrict__ out,
                                               int nsplit) {
    int idx = blockIdx.x * 256 + threadIdx.x;    // N_SEQ*16
    int row = idx >> 4, d4 = idx & 15;
    float M = -1e30f;
    for (int c = 0; c < nsplit; ++c) M = fmaxf(M, mpart[c * N_SEQ + row]);
    float4 num = make_float4(0.f, 0.f, 0.f, 0.f);
    float den = 0.f;
    for (int c = 0; c < nsplit; ++c) {
        float w = exp2f(mpart[c * N_SEQ + row] - M);
        den += w * lpart[c * N_SEQ + row];
        ushort4 o = ((const ushort4*)Opart)[((size_t)c * N_SEQ + row) * 16 + d4];
        num.x += w * bf2f(o.x); num.y += w * bf2f(o.y);
        num.z += w * bf2f(o.z); num.w += w * bf2f(o.w);
    }
    float inv = 1.0f / den;
    num.x *= inv; num.y *= inv; num.z *= inv; num.w *= inv;
    ((float4*)out)[idx] = num;
}

extern "C" void kernel_launch(void* const* d_in, const int* in_sizes, int n_in,
                              void* d_out, int out_size, void* d_ws, size_t ws_size,
                              hipStream_t stream) {
    const float* X  = (const float*)d_in[0];
    const float* WQ = (const float*)d_in[1];
    const float* WK = (const float*)d_in[2];
    const float* WV = (const float*)d_in[3];
    float* out = (float*)d_out;

    // workspace carve
    const size_t szQK = (size_t)N_SEQ * 64 * 2;      // 1 MB each (bf16)
    const size_t szW  = (size_t)192 * E_DIM * 2;     // 288 KB each
    char* p = (char*)d_ws;
    unsigned short* Qhi = (unsigned short*)p; p += szQK;
    unsigned short* Qlo = (unsigned short*)p; p += szQK;
    unsigned short* Khi = (unsigned short*)p; p += szQK;
    unsigned short* Klo = (unsigned short*)p; p += szQK;
    unsigned short* Vt  = (unsigned short*)p; p += szQK;
    unsigned short* Wthi = (unsigned short*)p; p += szW;
    unsigned short* Wtlo = (unsigned short*)p; p += szW;
    size_t base = (size_t)(p - (char*)d_ws);
    size_t per  = (size_t)N_SEQ * 64 * 2 + 2 * (size_t)N_SEQ * 4;  // Opart(bf16) + m + l per split
    int nsplit = 16;
    while (nsplit > 1 && base + (size_t)nsplit * per > ws_size) nsplit >>= 1;
    float* mpart = (float*)p; p += (size_t)nsplit * N_SEQ * 4;
    float* lpart = (float*)p; p += (size_t)nsplit * N_SEQ * 4;
    unsigned short* Opart = (unsigned short*)p;

    int chunk = N_SEQ / nsplit;

    prep_w<<<(192 * E_DIM + 255) / 256, 256, 0, stream>>>(WQ, WK, WV, Wthi, Wtlo);
    proj_qkv<<<512, 256, 0, stream>>>(X, Wthi, Wtlo, Qhi, Qlo, Khi, Klo, Vt);
    // MEASUREMENT PROBE (this round only): 4 extra idempotent proj launches.
    // (total - 168.6)/4 = proj duration + per-dispatch overhead, amplified 4x
    // above the +-3us noise. Decision rule pre-committed in the journal.
    proj_qkv<<<512, 256, 0, stream>>>(X, Wthi, Wtlo, Qhi, Qlo, Khi, Klo, Vt);
    proj_qkv<<<512, 256, 0, stream>>>(X, Wthi, Wtlo, Qhi, Qlo, Khi, Klo, Vt);
    proj_qkv<<<512, 256, 0, stream>>>(X, Wthi, Wtlo, Qhi, Qlo, Khi, Klo, Vt);
    proj_qkv<<<512, 256, 0, stream>>>(X, Wthi, Wtlo, Qhi, Qlo, Khi, Klo, Vt);
    attn<<<dim3(nsplit, N_SEQ / 128), 256, 0, stream>>>(Qhi, Qlo, Khi, Klo, Vt,
                                                        Opart, mpart, lpart, chunk);
    combine<<<(N_SEQ * 16 + 255) / 256, 256, 0, stream>>>(Opart, mpart, lpart, out, nsplit);
}

// Round 11
// 170.231 us; speedup vs baseline: 1.8960x; 1.8960x over previous
//
#include <hip/hip_runtime.h>
#include <hip/hip_fp16.h>

#define N_SEQ 8192
#define E_DIM 768
#define D_OUT 64
#define PADK 68                       // 64 + 4 pad -> 136B rows: 2-way (free) bank aliasing
#define SCALE_LOG2 0.18033688011112042f   // 1/(8*ln2): fold softmax scale + log2e into Q

typedef __attribute__((ext_vector_type(8)))  short s16x8;
typedef __attribute__((ext_vector_type(4)))  float f32x4;
typedef __attribute__((ext_vector_type(16))) float f32x16;

static __device__ __forceinline__ unsigned short f2bf(float f) {
    union { float f; unsigned int u; } v; v.f = f;
    unsigned int r = v.u + 0x7FFFu + ((v.u >> 16) & 1u);   // RNE
    return (unsigned short)(r >> 16);
}
static __device__ __forceinline__ float bf2f(unsigned short h) {
    union { float f; unsigned int u; } v; v.u = ((unsigned int)h) << 16; return v.f;
}
// pack two f32 -> bf16x2 by truncation (bias cancels: same P feeds O and l)
static __device__ __forceinline__ unsigned int packbf(float a, float b) {
    union { float f; unsigned int u; } x, y; x.f = a; y.f = b;
    return (y.u & 0xFFFF0000u) | (x.u >> 16);
}
static __device__ __forceinline__ s16x8 gfrag(const unsigned short* p) {
    union { uint4 u; s16x8 s; } r; r.u = *(const uint4*)p; return r.s;
}
static __device__ __forceinline__ s16x8 ldsfrag(const unsigned short* p) {
    union { uint2 u[2]; s16x8 s; } r;
    r.u[0] = *(const uint2*)(p);
    r.u[1] = *(const uint2*)(p + 4);
    return r.s;
}
static __device__ __forceinline__ void st32(unsigned short* d, uint4 a, uint4 b) {
    uint2* p = (uint2*)d;
    p[0] = make_uint2(a.x, a.y); p[1] = make_uint2(a.z, a.w);
    p[2] = make_uint2(b.x, b.y); p[3] = make_uint2(b.z, b.w);
}

// ---------------- Kernel 1: W -> Wt (transposed, bf16 hi/lo) -----------------
__global__ __launch_bounds__(256) void prep_w(const float* __restrict__ WQ,
                                              const float* __restrict__ WK,
                                              const float* __restrict__ WV,
                                              unsigned short* __restrict__ Wthi,
                                              unsigned short* __restrict__ Wtlo) {
    int idx = blockIdx.x * 256 + threadIdx.x;          // 192*768 total
    if (idx >= 192 * E_DIM) return;
    int n = idx / E_DIM;
    int k = idx - n * E_DIM;
    float v;
    if (n < 64)       v = WQ[k * 64 + n];
    else if (n < 128) v = WK[k * 64 + (n - 64)];
    else              v = WV[k * 64 + (n - 128)];
    unsigned short hb = f2bf(v);
    Wthi[idx] = hb;
    Wtlo[idx] = f2bf(v - bf2f(hb));
}

// ---------------- Kernel 2: QKV projection, K-split x2 -----------------------
// Round-10 probe: old proj (512 blocks, 8 waves/CU, no staging) = 38.5us,
// ~3x its traffic roofline -> latency-bound. Task count capped waves/CU at 8,
// so K-split x2: wave-task = (mt, c, khalf), khalf covers 384 of E_DIM.
// Both khalves share a 128-thread block; wave1's 12 partial f32 go through
// LDS (stride-13, conflict-free), wave0 reduces + runs the old epilogue.
// 2048 blocks x 128thr, bounds(128,4) -> 8 blocks/CU = 16 waves/CU.
__global__ __launch_bounds__(128, 4) void proj_qkv(const float* __restrict__ X,
                                                   const unsigned short* __restrict__ Wthi,
                                                   const unsigned short* __restrict__ Wtlo,
                                                   unsigned short* __restrict__ Qhi,
                                                   unsigned short* __restrict__ Qlo,
                                                   unsigned short* __restrict__ Khi,
                                                   unsigned short* __restrict__ Klo,
                                                   unsigned short* __restrict__ Vt) {
    __shared__ float red[64 * 13];           // wave1 partials, stride 13 (gcd(13,32)=1)

    int tid  = threadIdx.x;
    int wv   = tid >> 6;                     // khalf 0/1
    int lane = tid & 63;
    int id   = blockIdx.x;                   // 0..2047
    int mt   = id >> 2;
    int c    = id & 3;                       // 16-col block within D=64
    int m0 = mt * 16, n0 = c * 16;
    int lr = lane & 15, lk = lane >> 4;      // row-in-tile, k-quad
    int k0 = wv * (E_DIM / 2);               // this wave's K-half

    f32x4 aQ, aK, aV;
    #pragma unroll
    for (int i = 0; i < 4; ++i) { aQ[i] = 0.f; aK[i] = 0.f; aV[i] = 0.f; }

    const float*          xp  = X    + (size_t)(m0 + lr) * E_DIM + k0 + lk * 8;
    const unsigned short* wqh = Wthi + (size_t)(n0 + lr) * E_DIM + k0 + lk * 8;
    const unsigned short* wql = Wtlo + (size_t)(n0 + lr) * E_DIM + k0 + lk * 8;
    const unsigned short* wkh = Wthi + (size_t)(64 + n0 + lr) * E_DIM + k0 + lk * 8;
    const unsigned short* wkl = Wtlo + (size_t)(64 + n0 + lr) * E_DIM + k0 + lk * 8;
    const unsigned short* wvh = Wthi + (size_t)(128 + n0 + lr) * E_DIM + k0 + lk * 8;

    #pragma unroll 2
    for (int ks = 0; ks < E_DIM / 64; ++ks) {    // 12 k-steps of 32
        int kb = ks * 32;
        float4 x0 = *(const float4*)(xp + kb);
        float4 x1 = *(const float4*)(xp + kb + 4);
        s16x8 bqh = gfrag(wqh + kb);
        s16x8 bql = gfrag(wql + kb);
        s16x8 bkh = gfrag(wkh + kb);
        s16x8 bkl = gfrag(wkl + kb);
        s16x8 bvh = gfrag(wvh + kb);
        // split X f32 -> hi/lo bf16 fragments (bit-identical to old prep_x)
        float xs[8] = { x0.x, x0.y, x0.z, x0.w, x1.x, x1.y, x1.z, x1.w };
        union { unsigned short u[8]; s16x8 s; } ah, al;
        #pragma unroll
        for (int i = 0; i < 8; ++i) {
            unsigned short hb = f2bf(xs[i]);
            ah.u[i] = hb;
            al.u[i] = f2bf(xs[i] - bf2f(hb));
        }
        aQ = __builtin_amdgcn_mfma_f32_16x16x32_bf16(ah.s, bqh, aQ, 0, 0, 0);
        aK = __builtin_amdgcn_mfma_f32_16x16x32_bf16(ah.s, bkh, aK, 0, 0, 0);
        aV = __builtin_amdgcn_mfma_f32_16x16x32_bf16(ah.s, bvh, aV, 0, 0, 0);
        aQ = __builtin_amdgcn_mfma_f32_16x16x32_bf16(ah.s, bql, aQ, 0, 0, 0);
        aK = __builtin_amdgcn_mfma_f32_16x16x32_bf16(ah.s, bkl, aK, 0, 0, 0);
        aQ = __builtin_amdgcn_mfma_f32_16x16x32_bf16(al.s, bqh, aQ, 0, 0, 0);
        aK = __builtin_amdgcn_mfma_f32_16x16x32_bf16(al.s, bkh, aK, 0, 0, 0);
    }

    // cross-khalf reduce: wave1 -> LDS, wave0 adds (exact: a+b has one rounding)
    if (wv == 1) {
        float* r = red + lane * 13;
        #pragma unroll
        for (int i = 0; i < 4; ++i) { r[i] = aQ[i]; r[4 + i] = aK[i]; r[8 + i] = aV[i]; }
    }
    __syncthreads();
    if (wv == 1) return;
    {
        const float* r = red + lane * 13;
        #pragma unroll
        for (int i = 0; i < 4; ++i) { aQ[i] += r[i]; aK[i] += r[4 + i]; aV[i] += r[8 + i]; }
    }

    // C/D layout (16x16): col = lane&15, row = (lane>>4)*4 + r  [m89/m91]
    #pragma unroll
    for (int r = 0; r < 4; ++r) {
        int grow = m0 + lk * 4 + r, gcol = n0 + lr;
        float q = aQ[r] * SCALE_LOG2;
        unsigned short hb = f2bf(q);
        Qhi[(size_t)grow * 64 + gcol] = hb;
        Qlo[(size_t)grow * 64 + gcol] = f2bf(q - bf2f(hb));
        float v = aK[r];
        hb = f2bf(v);
        Khi[(size_t)grow * 64 + gcol] = hb;
        Klo[(size_t)grow * 64 + gcol] = f2bf(v - bf2f(hb));
    }
    ushort4 pk;                          // V: 4 consecutive rows -> one 8B store
    pk.x = f2bf(aV[0]); pk.y = f2bf(aV[1]);
    pk.z = f2bf(aV[2]); pk.w = f2bf(aV[3]);
    *(ushort4*)(Vt + (size_t)(n0 + lr) * N_SEQ + m0 + lk * 4) = pk;
}

// ---------------- Kernel 3: flash attention (round-0 body, bf16 Opart) -------
// grid (nsplit, 64); block 256 = 4 waves x 32 Q-rows; PADK layout (0 conflicts).
// __launch_bounds__(256,3): REQUIRED -- (256,4) makes hipcc clamp to 64 VGPR
// and spill to scratch (rounds 4 & 7). P half-swap: verified shfl_xor path
// (v_permlane32_swap retired -- both operand orientations failed on HW, r1/r9).
__global__ __launch_bounds__(256, 3) void attn(const unsigned short* __restrict__ Qhi,
                                               const unsigned short* __restrict__ Qlo,
                                               const unsigned short* __restrict__ Khi,
                                               const unsigned short* __restrict__ Klo,
                                               const unsigned short* __restrict__ Vt,
                                               unsigned short* __restrict__ Opart,
                                               float* __restrict__ mpart,
                                               float* __restrict__ lpart,
                                               int chunk) {
    __shared__ unsigned short sK[128 * PADK];   // rows 0-63 Khi, 64-127 Klo
    __shared__ unsigned short sV [64 * PADK];   // [d][key]

    int tid = threadIdx.x, wv = tid >> 6, lane = tid & 63;
    int lrow = lane & 31, lh = lane >> 5;
    int c = blockIdx.x, qb = blockIdx.y;
    int q0 = qb * 128 + wv * 32;

    // Q fragments (whole D=64) resident in registers
    s16x8 qh[4], ql[4];
    #pragma unroll
    for (int ks = 0; ks < 4; ++ks) {
        int kb = ks * 16 + lh * 8;
        qh[ks] = gfrag(Qhi + (size_t)(q0 + lrow) * 64 + kb);
        ql[ks] = gfrag(Qlo + (size_t)(q0 + lrow) * 64 + kb);
    }

    f32x16 O0, O1;
    #pragma unroll
    for (int i = 0; i < 16; ++i) { O0[i] = 0.f; O1[i] = 0.f; }
    float mrow = -1e30f, lrun = 0.f;

    int steps = chunk >> 6;
    int srow = tid >> 2, sseg = tid & 3;    // staging: 64 rows x 4 segs x 16 elems

    // prefetch tile 0
    uint4 rA0, rA1, rB0, rB1, rC0, rC1;
    {
        int j1 = c * chunk;
        const uint4* ps = (const uint4*)(Khi + ((size_t)(j1 + srow) * 64 + sseg * 16));
        rA0 = ps[0]; rA1 = ps[1];
        ps = (const uint4*)(Klo + ((size_t)(j1 + srow) * 64 + sseg * 16));
        rB0 = ps[0]; rB1 = ps[1];
        ps = (const uint4*)(Vt + ((size_t)srow * N_SEQ + j1 + sseg * 16));
        rC0 = ps[0]; rC1 = ps[1];
    }

    for (int it = 0; it < steps; ++it) {
        __syncthreads();                     // all waves done reading prev tile
        st32(sK + srow * PADK + sseg * 16, rA0, rA1);
        st32(sK + (64 + srow) * PADK + sseg * 16, rB0, rB1);
        st32(sV + srow * PADK + sseg * 16, rC0, rC1);
        __syncthreads();

        if (it + 1 < steps) {                // prefetch next tile (waits at next st32)
            int j1 = c * chunk + (it + 1) * 64;
            const uint4* ps = (const uint4*)(Khi + ((size_t)(j1 + srow) * 64 + sseg * 16));
            rA0 = ps[0]; rA1 = ps[1];
            ps = (const uint4*)(Klo + ((size_t)(j1 + srow) * 64 + sseg * 16));
            rB0 = ps[0]; rB1 = ps[1];
            ps = (const uint4*)(Vt + ((size_t)srow * N_SEQ + j1 + sseg * 16));
            rC0 = ps[0]; rC1 = ps[1];
        }

        // S^T = K @ Q^T  (3-term split-bf16): s0 keys 0-31, s1 keys 32-63
        f32x16 s0, s1;
        #pragma unroll
        for (int i = 0; i < 16; ++i) { s0[i] = 0.f; s1[i] = 0.f; }
        #pragma unroll
        for (int ks = 0; ks < 4; ++ks) {
            int kb = ks * 16 + lh * 8;
            s16x8 b0h = ldsfrag(sK + (size_t)lrow * PADK + kb);
            s16x8 b0l = ldsfrag(sK + (size_t)(64 + lrow) * PADK + kb);
            s0 = __builtin_amdgcn_mfma_f32_32x32x16_bf16(b0h, qh[ks], s0, 0, 0, 0);
            s0 = __builtin_amdgcn_mfma_f32_32x32x16_bf16(b0l, qh[ks], s0, 0, 0, 0);
            s0 = __builtin_amdgcn_mfma_f32_32x32x16_bf16(b0h, ql[ks], s0, 0, 0, 0);
            s16x8 b1h = ldsfrag(sK + (size_t)(32 + lrow) * PADK + kb);
            s16x8 b1l = ldsfrag(sK + (size_t)(96 + lrow) * PADK + kb);
            s1 = __builtin_amdgcn_mfma_f32_32x32x16_bf16(b1h, qh[ks], s1, 0, 0, 0);
            s1 = __builtin_amdgcn_mfma_f32_32x32x16_bf16(b1l, qh[ks], s1, 0, 0, 0);
            s1 = __builtin_amdgcn_mfma_f32_32x32x16_bf16(b1h, ql[ks], s1, 0, 0, 0);
        }

        // in-lane row max (this lane's query = lrow; 32 of 64 keys per half)
        float rm = s0[0];
        #pragma unroll
        for (int i = 1; i < 16; ++i) rm = fmaxf(rm, s0[i]);
        #pragma unroll
        for (int i = 0; i < 16; ++i) rm = fmaxf(rm, s1[i]);
        rm = fmaxf(rm, __shfl_xor(rm, 32, 64));
        float mn  = fmaxf(mrow, rm);
        float alf = exp2f(mrow - mn);
        mrow = mn;

        // p = exp2(s - m) in place; partial row-sum
        float psum = 0.f;
        #pragma unroll
        for (int i = 0; i < 16; ++i) { s0[i] = exp2f(s0[i] - mn); psum += s0[i]; }
        #pragma unroll
        for (int i = 0; i < 16; ++i) { s1[i] = exp2f(s1[i] - mn); psum += s1[i]; }
        lrun = lrun * alf + psum;

        // pack P to bf16 pairs; swap halves via lane^32 to build A-frags
        unsigned int I[16], J[16];
        #pragma unroll
        for (int q4 = 0; q4 < 4; ++q4) {
            I[2 * q4]     = packbf(s0[4 * q4],     s0[4 * q4 + 1]);
            I[2 * q4 + 1] = packbf(s0[4 * q4 + 2], s0[4 * q4 + 3]);
            I[8 + 2 * q4]     = packbf(s1[4 * q4],     s1[4 * q4 + 1]);
            I[8 + 2 * q4 + 1] = packbf(s1[4 * q4 + 2], s1[4 * q4 + 3]);
        }
        #pragma unroll
        for (int i = 0; i < 16; ++i) J[i] = (unsigned int)__shfl_xor((int)I[i], 32, 64);
        s16x8 a[4];
        #pragma unroll
        for (int ks = 0; ks < 4; ++ks) {
            int b = (ks >> 1) * 8 + (ks & 1) * 4;
            union { unsigned int u[4]; s16x8 s; } fa;
            fa.u[0] = lh ? J[b + 2] : I[b];
            fa.u[1] = lh ? J[b + 3] : I[b + 1];
            fa.u[2] = lh ? I[b + 2] : J[b];
            fa.u[3] = lh ? I[b + 3] : J[b + 1];
            a[ks] = fa.s;
        }

        // rescale O by alpha of each O-row's query (fetch via bpermute)
        #pragma unroll
        for (int r = 0; r < 16; ++r) {
            int qr = (r & 3) + 8 * (r >> 2) + 4 * lh;
            float af = __shfl(alf, qr, 64);
            O0[r] *= af; O1[r] *= af;
        }

        // O += P @ V
        #pragma unroll
        for (int ks = 0; ks < 4; ++ks) {
            int kb = ks * 16 + lh * 8;
            s16x8 b0 = ldsfrag(sV + (size_t)lrow * PADK + kb);
            s16x8 b1 = ldsfrag(sV + (size_t)(32 + lrow) * PADK + kb);
            O0 = __builtin_amdgcn_mfma_f32_32x32x16_bf16(a[ks], b0, O0, 0, 0, 0);
            O1 = __builtin_amdgcn_mfma_f32_32x32x16_bf16(a[ks], b1, O1, 0, 0, 0);
        }
    }

    // store partials (bf16)
    #pragma unroll
    for (int r = 0; r < 16; ++r) {
        int row = (r & 3) + 8 * (r >> 2) + 4 * lh;
        int grow = q0 + row;
        size_t ob = ((size_t)c * N_SEQ + grow) * 64;
        Opart[ob + lrow]      = f2bf(O0[r]);
        Opart[ob + 32 + lrow] = f2bf(O1[r]);
    }
    float lfull = lrun + __shfl_xor(lrun, 32, 64);
    if (lane < 32) {
        int grow = q0 + lrow;
        mpart[c * N_SEQ + grow] = mrow;
        lpart[c * N_SEQ + grow] = lfull;
    }
}

// ---------------- Kernel 4: combine split-K partials (bf16 in, f32 out) ------
__global__ __launch_bounds__(256) void combine(const unsigned short* __restrict__ Opart,
                                               const float* __restrict__ mpart,
                                               const float* __restrict__ lpart,
                                               float* __restrict__ out,
                                               int nsplit) {
    int idx = blockIdx.x * 256 + threadIdx.x;    // N_SEQ*16
    int row = idx >> 4, d4 = idx & 15;
    float M = -1e30f;
    for (int c = 0; c < nsplit; ++c) M = fmaxf(M, mpart[c * N_SEQ + row]);
    float4 num = make_float4(0.f, 0.f, 0.f, 0.f);
    float den = 0.f;
    for (int c = 0; c < nsplit; ++c) {
        float w = exp2f(mpart[c * N_SEQ + row] - M);
        den += w * lpart[c * N_SEQ + row];
        ushort4 o = ((const ushort4*)Opart)[((size_t)c * N_SEQ + row) * 16 + d4];
        num.x += w * bf2f(o.x); num.y += w * bf2f(o.y);
        num.z += w * bf2f(o.z); num.w += w * bf2f(o.w);
    }
    float inv = 1.0f / den;
    num.x *= inv; num.y *= inv; num.z *= inv; num.w *= inv;
    ((float4*)out)[idx] = num;
}

extern "C" void kernel_launch(void* const* d_in, const int* in_sizes, int n_in,
                              void* d_out, int out_size, void* d_ws, size_t ws_size,
                              hipStream_t stream) {
    const float* X  = (const float*)d_in[0];
    const float* WQ = (const float*)d_in[1];
    const float* WK = (const float*)d_in[2];
    const float* WV = (const float*)d_in[3];
    float* out = (float*)d_out;

    // workspace carve
    const size_t szQK = (size_t)N_SEQ * 64 * 2;      // 1 MB each (bf16)
    const size_t szW  = (size_t)192 * E_DIM * 2;     // 288 KB each
    char* p = (char*)d_ws;
    unsigned short* Qhi = (unsigned short*)p; p += szQK;
    unsigned short* Qlo = (unsigned short*)p; p += szQK;
    unsigned short* Khi = (unsigned short*)p; p += szQK;
    unsigned short* Klo = (unsigned short*)p; p += szQK;
    unsigned short* Vt  = (unsigned short*)p; p += szQK;
    unsigned short* Wthi = (unsigned short*)p; p += szW;
    unsigned short* Wtlo = (unsigned short*)p; p += szW;
    size_t base = (size_t)(p - (char*)d_ws);
    size_t per  = (size_t)N_SEQ * 64 * 2 + 2 * (size_t)N_SEQ * 4;  // Opart(bf16) + m + l per split
    int nsplit = 16;
    while (nsplit > 1 && base + (size_t)nsplit * per > ws_size) nsplit >>= 1;
    float* mpart = (float*)p; p += (size_t)nsplit * N_SEQ * 4;
    float* lpart = (float*)p; p += (size_t)nsplit * N_SEQ * 4;
    unsigned short* Opart = (unsigned short*)p;

    int chunk = N_SEQ / nsplit;

    prep_w<<<(192 * E_DIM + 255) / 256, 256, 0, stream>>>(WQ, WK, WV, Wthi, Wtlo);
    proj_qkv<<<2048, 128, 0, stream>>>(X, Wthi, Wtlo, Qhi, Qlo, Khi, Klo, Vt);
    attn<<<dim3(nsplit, N_SEQ / 128), 256, 0, stream>>>(Qhi, Qlo, Khi, Klo, Vt,
                                                        Opart, mpart, lpart, chunk);
    combine<<<(N_SEQ * 16 + 255) / 256, 256, 0, stream>>>(Opart, mpart, lpart, out, nsplit);
}

// Round 12
// 143.779 us; speedup vs baseline: 2.2448x; 1.1840x over previous
//
#include <hip/hip_runtime.h>
#include <hip/hip_fp16.h>

#define N_SEQ 8192
#define E_DIM 768
#define D_OUT 64
#define PADK 68                       // 64 + 4 pad -> 136B rows: 2-way (free) bank aliasing
#define SCALE_LOG2 0.18033688011112042f   // 1/(8*ln2): fold softmax scale + log2e into Q

typedef __attribute__((ext_vector_type(8)))  short s16x8;
typedef __attribute__((ext_vector_type(4)))  float f32x4;
typedef __attribute__((ext_vector_type(16))) float f32x16;

static __device__ __forceinline__ unsigned short f2bf(float f) {
    union { float f; unsigned int u; } v; v.f = f;
    unsigned int r = v.u + 0x7FFFu + ((v.u >> 16) & 1u);   // RNE
    return (unsigned short)(r >> 16);
}
static __device__ __forceinline__ float bf2f(unsigned short h) {
    union { float f; unsigned int u; } v; v.u = ((unsigned int)h) << 16; return v.f;
}
// pack two f32 -> bf16x2 by truncation (bias cancels: same P feeds O and l)
static __device__ __forceinline__ unsigned int packbf(float a, float b) {
    union { float f; unsigned int u; } x, y; x.f = a; y.f = b;
    return (y.u & 0xFFFF0000u) | (x.u >> 16);
}
static __device__ __forceinline__ s16x8 gfrag(const unsigned short* p) {
    union { uint4 u; s16x8 s; } r; r.u = *(const uint4*)p; return r.s;
}
static __device__ __forceinline__ s16x8 ldsq(const unsigned short* p) {
    union { uint4 u; s16x8 s; } r; r.u = *(const uint4*)p; return r.s;
}
static __device__ __forceinline__ s16x8 ldsfrag(const unsigned short* p) {
    union { uint2 u[2]; s16x8 s; } r;
    r.u[0] = *(const uint2*)(p);
    r.u[1] = *(const uint2*)(p + 4);
    return r.s;
}
static __device__ __forceinline__ void st32(unsigned short* d, uint4 a, uint4 b) {
    uint2* p = (uint2*)d;
    p[0] = make_uint2(a.x, a.y); p[1] = make_uint2(a.z, a.w);
    p[2] = make_uint2(b.x, b.y); p[3] = make_uint2(b.z, b.w);
}

// ---------------- Kernel 1: W -> MFMA-fragment-ordered bf16 hi/lo ------------
// Layout: Wf[((nblk*24 + ks)*64 + lane)*8 + e], nblk = n/16 (0-3 Q, 4-7 K,
// 8-11 V), lane = lk*16 + lr (the 16x16x32 A/B-frag lane mapping), ks = k/32,
// lk = (k%32)/8, e = k%8. proj's W loads become 16B/lane fully-coalesced.
__global__ __launch_bounds__(256) void prep_w(const float* __restrict__ WQ,
                                              const float* __restrict__ WK,
                                              const float* __restrict__ WV,
                                              unsigned short* __restrict__ Wfh,
                                              unsigned short* __restrict__ Wfl) {
    int idx = blockIdx.x * 256 + threadIdx.x;          // 192*768 total
    if (idx >= 192 * E_DIM) return;
    int n = idx / E_DIM;
    int k = idx - n * E_DIM;
    float v;
    if (n < 64)       v = WQ[k * 64 + n];
    else if (n < 128) v = WK[k * 64 + (n - 64)];
    else              v = WV[k * 64 + (n - 128)];
    int nblk = n >> 4, lr = n & 15;
    int ks = k >> 5, lk = (k >> 3) & 3, e = k & 7;
    size_t pos = ((size_t)(nblk * 24 + ks) * 64 + lk * 16 + lr) * 8 + e;
    unsigned short hb = f2bf(v);
    Wfh[pos] = hb;
    Wfl[pos] = f2bf(v - bf2f(hb));
}

// ---------------- Kernel 2: QKV projection (LDS-staged X, coalesced W) -------
// Round-11 diagnosis: old proj's loads hit 16 rows at 1536B stride per wave
// instruction (~16 cache-line transactions each) -> TA/L2-transaction-bound
// (38.5us measured by r10 probe; latency [r11 K-split] and traffic models
// both acquitted). Fix: X staged via LDS with CONTIGUOUS float4 reads and
// converted once per block (not per wave); W pre-arranged in fragment order
// by prep_w. Every inner-loop access is now coalesced / conflict-free.
// MFMA order identical to round 8 -> Q/K/V bit-identical (absmax check: 0.5).
__global__ __launch_bounds__(256, 2) void proj_qkv(const float* __restrict__ X,
                                                   const unsigned short* __restrict__ Wfh,
                                                   const unsigned short* __restrict__ Wfl,
                                                   unsigned short* __restrict__ Qhi,
                                                   unsigned short* __restrict__ Qlo,
                                                   unsigned short* __restrict__ Khi,
                                                   unsigned short* __restrict__ Klo,
                                                   unsigned short* __restrict__ Vt) {
    __shared__ unsigned short sXh[24 * 64 * 8];   // 24 KB, frag order [ks][lane][8]
    __shared__ unsigned short sXl[24 * 64 * 8];   // 24 KB

    int tid  = threadIdx.x;
    int wv   = tid >> 6;                     // = c (16-col block within D=64)
    int lane = tid & 63;
    int mt   = blockIdx.x;                   // 0..511
    int m0 = mt * 16, n0 = wv * 16;
    int lr = lane & 15, lk = lane >> 4;      // row-in-tile, k-quad

    // ---- stage X block (16 x 768 f32) -> hi/lo bf16 fragments in LDS ----
    // thread t, iter it: float4 #(it*256+t) of the contiguous 16x768 block.
    {
        const float4* xb = (const float4*)(X + (size_t)m0 * E_DIM);
        #pragma unroll
        for (int it = 0; it < 12; ++it) {
            int f4 = it * 256 + tid;             // 0..3071
            int r  = f4 / 192;                   // row in tile
            int kb4 = (f4 - r * 192) * 4;        // first col (mult of 4)
            float4 v = xb[f4];
            int ksx = kb4 >> 5, lkx = (kb4 >> 3) & 3, e0 = kb4 & 7;  // e0 = 0 or 4
            int ln  = lkx * 16 + r;
            ushort4 hi, lo;
            hi.x = f2bf(v.x); lo.x = f2bf(v.x - bf2f(hi.x));
            hi.y = f2bf(v.y); lo.y = f2bf(v.y - bf2f(hi.y));
            hi.z = f2bf(v.z); lo.z = f2bf(v.z - bf2f(hi.z));
            hi.w = f2bf(v.w); lo.w = f2bf(v.w - bf2f(hi.w));
            int p = (ksx * 64 + ln) * 8 + e0;
            *(ushort4*)(sXh + p) = hi;
            *(ushort4*)(sXl + p) = lo;
        }
    }
    __syncthreads();

    f32x4 aQ, aK, aV;
    #pragma unroll
    for (int i = 0; i < 4; ++i) { aQ[i] = 0.f; aK[i] = 0.f; aV[i] = 0.f; }

    const unsigned short* wq = Wfh + ((size_t)(wv * 24) * 64 + lane) * 8;
    const unsigned short* wqL = Wfl + ((size_t)(wv * 24) * 64 + lane) * 8;
    const unsigned short* wk = Wfh + ((size_t)((4 + wv) * 24) * 64 + lane) * 8;
    const unsigned short* wkL = Wfl + ((size_t)((4 + wv) * 24) * 64 + lane) * 8;
    const unsigned short* wvp = Wfh + ((size_t)((8 + wv) * 24) * 64 + lane) * 8;

    #pragma unroll 2
    for (int ks = 0; ks < 24; ++ks) {
        const unsigned short* xs = sXh + (ks * 64 + lane) * 8;
        s16x8 ah = ldsq(xs);
        s16x8 al = ldsq(sXl + (ks * 64 + lane) * 8);
        size_t wo = (size_t)ks * 64 * 8;
        s16x8 bqh = gfrag(wq + wo);
        s16x8 bql = gfrag(wqL + wo);
        s16x8 bkh = gfrag(wk + wo);
        s16x8 bkl = gfrag(wkL + wo);
        s16x8 bvh = gfrag(wvp + wo);
        aQ = __builtin_amdgcn_mfma_f32_16x16x32_bf16(ah, bqh, aQ, 0, 0, 0);
        aK = __builtin_amdgcn_mfma_f32_16x16x32_bf16(ah, bkh, aK, 0, 0, 0);
        aV = __builtin_amdgcn_mfma_f32_16x16x32_bf16(ah, bvh, aV, 0, 0, 0);
        aQ = __builtin_amdgcn_mfma_f32_16x16x32_bf16(ah, bql, aQ, 0, 0, 0);
        aK = __builtin_amdgcn_mfma_f32_16x16x32_bf16(ah, bkl, aK, 0, 0, 0);
        aQ = __builtin_amdgcn_mfma_f32_16x16x32_bf16(al, bqh, aQ, 0, 0, 0);
        aK = __builtin_amdgcn_mfma_f32_16x16x32_bf16(al, bkh, aK, 0, 0, 0);
    }

    // C/D layout (16x16): col = lane&15, row = (lane>>4)*4 + r  [m89/m91]
    #pragma unroll
    for (int r = 0; r < 4; ++r) {
        int grow = m0 + lk * 4 + r, gcol = n0 + lr;
        float q = aQ[r] * SCALE_LOG2;
        unsigned short hb = f2bf(q);
        Qhi[(size_t)grow * 64 + gcol] = hb;
        Qlo[(size_t)grow * 64 + gcol] = f2bf(q - bf2f(hb));
        float v = aK[r];
        hb = f2bf(v);
        Khi[(size_t)grow * 64 + gcol] = hb;
        Klo[(size_t)grow * 64 + gcol] = f2bf(v - bf2f(hb));
    }
    ushort4 pk;                          // V: 4 consecutive rows -> one 8B store
    pk.x = f2bf(aV[0]); pk.y = f2bf(aV[1]);
    pk.z = f2bf(aV[2]); pk.w = f2bf(aV[3]);
    *(ushort4*)(Vt + (size_t)(n0 + lr) * N_SEQ + m0 + lk * 4) = pk;
}

// ---------------- Kernel 3: flash attention (round-0 body, bf16 Opart) -------
// grid (nsplit, 64); block 256 = 4 waves x 32 Q-rows; PADK layout (0 conflicts).
// __launch_bounds__(256,3): REQUIRED -- (256,4) makes hipcc clamp to 64 VGPR
// and spill to scratch (rounds 4 & 7). P half-swap: verified shfl_xor path
// (v_permlane32_swap retired -- both operand orientations failed on HW, r1/r9).
__global__ __launch_bounds__(256, 3) void attn(const unsigned short* __restrict__ Qhi,
                                               const unsigned short* __restrict__ Qlo,
                                               const unsigned short* __restrict__ Khi,
                                               const unsigned short* __restrict__ Klo,
                                               const unsigned short* __restrict__ Vt,
                                               unsigned short* __restrict__ Opart,
                                               float* __restrict__ mpart,
                                               float* __restrict__ lpart,
                                               int chunk) {
    __shared__ unsigned short sK[128 * PADK];   // rows 0-63 Khi, 64-127 Klo
    __shared__ unsigned short sV [64 * PADK];   // [d][key]

    int tid = threadIdx.x, wv = tid >> 6, lane = tid & 63;
    int lrow = lane & 31, lh = lane >> 5;
    int c = blockIdx.x, qb = blockIdx.y;
    int q0 = qb * 128 + wv * 32;

    // Q fragments (whole D=64) resident in registers
    s16x8 qh[4], ql[4];
    #pragma unroll
    for (int ks = 0; ks < 4; ++ks) {
        int kb = ks * 16 + lh * 8;
        qh[ks] = gfrag(Qhi + (size_t)(q0 + lrow) * 64 + kb);
        ql[ks] = gfrag(Qlo + (size_t)(q0 + lrow) * 64 + kb);
    }

    f32x16 O0, O1;
    #pragma unroll
    for (int i = 0; i < 16; ++i) { O0[i] = 0.f; O1[i] = 0.f; }
    float mrow = -1e30f, lrun = 0.f;

    int steps = chunk >> 6;
    int srow = tid >> 2, sseg = tid & 3;    // staging: 64 rows x 4 segs x 16 elems

    // prefetch tile 0
    uint4 rA0, rA1, rB0, rB1, rC0, rC1;
    {
        int j1 = c * chunk;
        const uint4* ps = (const uint4*)(Khi + ((size_t)(j1 + srow) * 64 + sseg * 16));
        rA0 = ps[0]; rA1 = ps[1];
        ps = (const uint4*)(Klo + ((size_t)(j1 + srow) * 64 + sseg * 16));
        rB0 = ps[0]; rB1 = ps[1];
        ps = (const uint4*)(Vt + ((size_t)srow * N_SEQ + j1 + sseg * 16));
        rC0 = ps[0]; rC1 = ps[1];
    }

    for (int it = 0; it < steps; ++it) {
        __syncthreads();                     // all waves done reading prev tile
        st32(sK + srow * PADK + sseg * 16, rA0, rA1);
        st32(sK + (64 + srow) * PADK + sseg * 16, rB0, rB1);
        st32(sV + srow * PADK + sseg * 16, rC0, rC1);
        __syncthreads();

        if (it + 1 < steps) {                // prefetch next tile (waits at next st32)
            int j1 = c * chunk + (it + 1) * 64;
            const uint4* ps = (const uint4*)(Khi + ((size_t)(j1 + srow) * 64 + sseg * 16));
            rA0 = ps[0]; rA1 = ps[1];
            ps = (const uint4*)(Klo + ((size_t)(j1 + srow) * 64 + sseg * 16));
            rB0 = ps[0]; rB1 = ps[1];
            ps = (const uint4*)(Vt + ((size_t)srow * N_SEQ + j1 + sseg * 16));
            rC0 = ps[0]; rC1 = ps[1];
        }

        // S^T = K @ Q^T  (3-term split-bf16): s0 keys 0-31, s1 keys 32-63
        f32x16 s0, s1;
        #pragma unroll
        for (int i = 0; i < 16; ++i) { s0[i] = 0.f; s1[i] = 0.f; }
        #pragma unroll
        for (int ks = 0; ks < 4; ++ks) {
            int kb = ks * 16 + lh * 8;
            s16x8 b0h = ldsfrag(sK + (size_t)lrow * PADK + kb);
            s16x8 b0l = ldsfrag(sK + (size_t)(64 + lrow) * PADK + kb);
            s0 = __builtin_amdgcn_mfma_f32_32x32x16_bf16(b0h, qh[ks], s0, 0, 0, 0);
            s0 = __builtin_amdgcn_mfma_f32_32x32x16_bf16(b0l, qh[ks], s0, 0, 0, 0);
            s0 = __builtin_amdgcn_mfma_f32_32x32x16_bf16(b0h, ql[ks], s0, 0, 0, 0);
            s16x8 b1h = ldsfrag(sK + (size_t)(32 + lrow) * PADK + kb);
            s16x8 b1l = ldsfrag(sK + (size_t)(96 + lrow) * PADK + kb);
            s1 = __builtin_amdgcn_mfma_f32_32x32x16_bf16(b1h, qh[ks], s1, 0, 0, 0);
            s1 = __builtin_amdgcn_mfma_f32_32x32x16_bf16(b1l, qh[ks], s1, 0, 0, 0);
            s1 = __builtin_amdgcn_mfma_f32_32x32x16_bf16(b1h, ql[ks], s1, 0, 0, 0);
        }

        // in-lane row max (this lane's query = lrow; 32 of 64 keys per half)
        float rm = s0[0];
        #pragma unroll
        for (int i = 1; i < 16; ++i) rm = fmaxf(rm, s0[i]);
        #pragma unroll
        for (int i = 0; i < 16; ++i) rm = fmaxf(rm, s1[i]);
        rm = fmaxf(rm, __shfl_xor(rm, 32, 64));
        float mn  = fmaxf(mrow, rm);
        float alf = exp2f(mrow - mn);
        mrow = mn;

        // p = exp2(s - m) in place; partial row-sum
        float psum = 0.f;
        #pragma unroll
        for (int i = 0; i < 16; ++i) { s0[i] = exp2f(s0[i] - mn); psum += s0[i]; }
        #pragma unroll
        for (int i = 0; i < 16; ++i) { s1[i] = exp2f(s1[i] - mn); psum += s1[i]; }
        lrun = lrun * alf + psum;

        // pack P to bf16 pairs; swap halves via lane^32 to build A-frags
        unsigned int I[16], J[16];
        #pragma unroll
        for (int q4 = 0; q4 < 4; ++q4) {
            I[2 * q4]     = packbf(s0[4 * q4],     s0[4 * q4 + 1]);
            I[2 * q4 + 1] = packbf(s0[4 * q4 + 2], s0[4 * q4 + 3]);
            I[8 + 2 * q4]     = packbf(s1[4 * q4],     s1[4 * q4 + 1]);
            I[8 + 2 * q4 + 1] = packbf(s1[4 * q4 + 2], s1[4 * q4 + 3]);
        }
        #pragma unroll
        for (int i = 0; i < 16; ++i) J[i] = (unsigned int)__shfl_xor((int)I[i], 32, 64);
        s16x8 a[4];
        #pragma unroll
        for (int ks = 0; ks < 4; ++ks) {
            int b = (ks >> 1) * 8 + (ks & 1) * 4;
            union { unsigned int u[4]; s16x8 s; } fa;
            fa.u[0] = lh ? J[b + 2] : I[b];
            fa.u[1] = lh ? J[b + 3] : I[b + 1];
            fa.u[2] = lh ? I[b + 2] : J[b];
            fa.u[3] = lh ? I[b + 3] : J[b + 1];
            a[ks] = fa.s;
        }

        // rescale O by alpha of each O-row's query (fetch via bpermute)
        #pragma unroll
        for (int r = 0; r < 16; ++r) {
            int qr = (r & 3) + 8 * (r >> 2) + 4 * lh;
            float af = __shfl(alf, qr, 64);
            O0[r] *= af; O1[r] *= af;
        }

        // O += P @ V
        #pragma unroll
        for (int ks = 0; ks < 4; ++ks) {
            int kb = ks * 16 + lh * 8;
            s16x8 b0 = ldsfrag(sV + (size_t)lrow * PADK + kb);
            s16x8 b1 = ldsfrag(sV + (size_t)(32 + lrow) * PADK + kb);
            O0 = __builtin_amdgcn_mfma_f32_32x32x16_bf16(a[ks], b0, O0, 0, 0, 0);
            O1 = __builtin_amdgcn_mfma_f32_32x32x16_bf16(a[ks], b1, O1, 0, 0, 0);
        }
    }

    // store partials (bf16)
    #pragma unroll
    for (int r = 0; r < 16; ++r) {
        int row = (r & 3) + 8 * (r >> 2) + 4 * lh;
        int grow = q0 + row;
        size_t ob = ((size_t)c * N_SEQ + grow) * 64;
        Opart[ob + lrow]      = f2bf(O0[r]);
        Opart[ob + 32 + lrow] = f2bf(O1[r]);
    }
    float lfull = lrun + __shfl_xor(lrun, 32, 64);
    if (lane < 32) {
        int grow = q0 + lrow;
        mpart[c * N_SEQ + grow] = mrow;
        lpart[c * N_SEQ + grow] = lfull;
    }
}

// ---------------- Kernel 4: combine split-K partials (bf16 in, f32 out) ------
__global__ __launch_bounds__(256) void combine(const unsigned short* __restrict__ Opart,
                                               const float* __restrict__ mpart,
                                               const float* __restrict__ lpart,
                                               float* __restrict__ out,
                                               int nsplit) {
    int idx = blockIdx.x * 256 + threadIdx.x;    // N_SEQ*16
    int row = idx >> 4, d4 = idx & 15;
    float M = -1e30f;
    for (int c = 0; c < nsplit; ++c) M = fmaxf(M, mpart[c * N_SEQ + row]);
    float4 num = make_float4(0.f, 0.f, 0.f, 0.f);
    float den = 0.f;
    for (int c = 0; c < nsplit; ++c) {
        float w = exp2f(mpart[c * N_SEQ + row] - M);
        den += w * lpart[c * N_SEQ + row];
        ushort4 o = ((const ushort4*)Opart)[((size_t)c * N_SEQ + row) * 16 + d4];
        num.x += w * bf2f(o.x); num.y += w * bf2f(o.y);
        num.z += w * bf2f(o.z); num.w += w * bf2f(o.w);
    }
    float inv = 1.0f / den;
    num.x *= inv; num.y *= inv; num.z *= inv; num.w *= inv;
    ((float4*)out)[idx] = num;
}

extern "C" void kernel_launch(void* const* d_in, const int* in_sizes, int n_in,
                              void* d_out, int out_size, void* d_ws, size_t ws_size,
                              hipStream_t stream) {
    const float* X  = (const float*)d_in[0];
    const float* WQ = (const float*)d_in[1];
    const float* WK = (const float*)d_in[2];
    const float* WV = (const float*)d_in[3];
    float* out = (float*)d_out;

    // workspace carve
    const size_t szQK = (size_t)N_SEQ * 64 * 2;      // 1 MB each (bf16)
    const size_t szW  = (size_t)192 * E_DIM * 2;     // 288 KB each
    char* p = (char*)d_ws;
    unsigned short* Qhi = (unsigned short*)p; p += szQK;
    unsigned short* Qlo = (unsigned short*)p; p += szQK;
    unsigned short* Khi = (unsigned short*)p; p += szQK;
    unsigned short* Klo = (unsigned short*)p; p += szQK;
    unsigned short* Vt  = (unsigned short*)p; p += szQK;
    unsigned short* Wfh = (unsigned short*)p; p += szW;
    unsigned short* Wfl = (unsigned short*)p; p += szW;
    size_t base = (size_t)(p - (char*)d_ws);
    size_t per  = (size_t)N_SEQ * 64 * 2 + 2 * (size_t)N_SEQ * 4;  // Opart(bf16) + m + l per split
    int nsplit = 16;
    while (nsplit > 1 && base + (size_t)nsplit * per > ws_size) nsplit >>= 1;
    float* mpart = (float*)p; p += (size_t)nsplit * N_SEQ * 4;
    float* lpart = (float*)p; p += (size_t)nsplit * N_SEQ * 4;
    unsigned short* Opart = (unsigned short*)p;

    int chunk = N_SEQ / nsplit;

    prep_w<<<(192 * E_DIM + 255) / 256, 256, 0, stream>>>(WQ, WK, WV, Wfh, Wfl);
    proj_qkv<<<512, 256, 0, stream>>>(X, Wfh, Wfl, Qhi, Qlo, Khi, Klo, Vt);
    attn<<<dim3(nsplit, N_SEQ / 128), 256, 0, stream>>>(Qhi, Qlo, Khi, Klo, Vt,
                                                        Opart, mpart, lpart, chunk);
    combine<<<(N_SEQ * 16 + 255) / 256, 256, 0, stream>>>(Opart, mpart, lpart, out, nsplit);
}